// Round 10
// baseline (44.036 us; speedup 1.0000x reference)
//
#include <hip/hip_runtime.h>
#include <math.h>

#define N 6144
#define E 64
#define H 8
#define D 512
#define TD 1536  // 3*D
#define EPS 1e-5f
#define SCALE 0.04419417382415922f  // 1/sqrt(512)
#define RMAX 80                     // max supported segment size

typedef __attribute__((ext_vector_type(8))) short bf16x8;
typedef __attribute__((ext_vector_type(4))) float f32x4;

static __device__ __forceinline__ unsigned short f2bf(float f) {
    union { float f; unsigned int u; } v; v.f = f;
    unsigned int r = v.u + 0x7FFFu + ((v.u >> 16) & 1u);  // RNE
    return (unsigned short)(r >> 16);
}
static __device__ __forceinline__ float bf2f(unsigned short u) {
    union { unsigned int u; float f; } v; v.u = ((unsigned int)u) << 16;
    return v.f;
}

// ---------------------------------------------------------------------------
// Kernel 0: prep (32 blocks). bound[257] from sorted batch; W_qkv -> Wt bf16
// [1536][64]; W_out -> Wot bf16 [64][512].
// ---------------------------------------------------------------------------
__global__ __launch_bounds__(256) void prep_kernel(
    const float* __restrict__ W_qkv, const float* __restrict__ W_out,
    const int* __restrict__ batch, unsigned short* __restrict__ Wt,
    unsigned short* __restrict__ Wot, int* __restrict__ bound)
{
    const int tid = blockIdx.x * 256 + threadIdx.x;
    if (tid < N) {
        const int bv = batch[tid];
        const int prev = tid ? batch[tid - 1] : -1;
        if (bv != prev)
            for (int v = prev + 1; v <= bv; ++v) bound[v] = tid;
        if (tid == N - 1)
            for (int v = bv + 1; v <= 256; ++v) bound[v] = N;
    }
    for (int i = tid; i < 64 * TD; i += 8192) {        // Wt[j][k] = W[k][j]
        const int k = i / TD, j = i - k * TD;
        Wt[j * 64 + k] = f2bf(W_qkv[i]);
    }
    for (int i = tid; i < 512 * 64; i += 8192) {       // Wot[j][k] = Wo[k][j]
        const int k = i >> 6, j = i & 63;
        Wot[j * 512 + k] = f2bf(W_out[i]);
    }
}

// ---------------------------------------------------------------------------
// Kernel 1: one block per (segment, head). LN1 recomputed in-block (into LDS
// overlaying Ps), QKV via MFMA from LDS, dense in-segment attention, O
// bounced through dead Ps rows for coalesced 16B stores.
// Frag maps (verified R3-R9): A[row=lr][k=lg*8+j], B[col=lr][k=lg*8+j],
// D[col=lr][row=lg*4+r].
// ---------------------------------------------------------------------------
__global__ __launch_bounds__(256, 3) void seghead_kernel(
    const float* __restrict__ x, const float* __restrict__ ln1g,
    const float* __restrict__ ln1b, const unsigned short* __restrict__ Wt,
    const float* __restrict__ b_qkv, const int* __restrict__ bound,
    unsigned short* __restrict__ attb)
{
    __shared__ unsigned short Qs[RMAX][72];     // per-head Q [q][d]
    __shared__ unsigned short Ks[RMAX][72];     // per-head K [key][d]
    __shared__ unsigned short Vs[64][104];      // per-head V^T [d][key]
    __shared__ unsigned short Ps[RMAX][104];    // P / O bounce; h1s overlay
    unsigned short (*h1s)[72] = (unsigned short(*)[72])Ps;  // LN1 out (QKV phase)

    const int t = threadIdx.x, lane = t & 63, wv = t >> 6;
    const int lr = lane & 15, lg = lane >> 4;
    const int b = blockIdx.x, h = blockIdx.y;

    // W fragments for this wave's column tile (independent of bound -> early)
    const int ct = wv;
    const int jK = h * 64 + ct * 16;
    const int jQ = 512 + jK;
    const int jV = 1024 + jK;
    const bf16x8 wK0 = *(const bf16x8*)&Wt[(size_t)(jK + lr) * 64 + lg * 8];
    const bf16x8 wK1 = *(const bf16x8*)&Wt[(size_t)(jK + lr) * 64 + 32 + lg * 8];
    const bf16x8 wQ0 = *(const bf16x8*)&Wt[(size_t)(jQ + lr) * 64 + lg * 8];
    const bf16x8 wQ1 = *(const bf16x8*)&Wt[(size_t)(jQ + lr) * 64 + 32 + lg * 8];
    const bf16x8 wV0 = *(const bf16x8*)&Wt[(size_t)(jV + lr) * 64 + lg * 8];
    const bf16x8 wV1 = *(const bf16x8*)&Wt[(size_t)(jV + lr) * 64 + 32 + lg * 8];
    const float bK = b_qkv[jK + lr];
    const float bQ = b_qkv[jQ + lr];
    const float bV = b_qkv[jV + lr];

    const int s = bound[b];
    int R = bound[b + 1] - s;
    if (R <= 0) return;                 // uniform across block (before syncs)
    if (R > RMAX) R = RMAX;             // safety clamp (P ~ 1e-19)
    const int NT = (R + 15) >> 4;       // 16-row tiles (1..5)
    const int RT = NT * 16;
    const int KB = (RT + 31) >> 5;      // 32-key blocks

    // ---- LN1 for this segment's rows (pad rows clamp to N-1) ----
    {
        const float gv = ln1g[lane], bv = ln1b[lane];
        for (int i = wv; i < RT; i += 4) {
            int row = s + i; row = row < N ? row : N - 1;
            const float v = x[(size_t)row * E + lane];
            float sm = v, sq = v * v;
            #pragma unroll
            for (int off = 1; off < 64; off <<= 1) {
                sm += __shfl_xor(sm, off);
                sq += __shfl_xor(sq, off);
            }
            const float mean = sm * (1.f / 64.f);
            const float var  = sq * (1.f / 64.f) - mean * mean;
            h1s[i][lane] = f2bf((v - mean) * rsqrtf(var + EPS) * gv + bv);
        }
    }
    // zero V^T tail key-cols [RT, KB*32): uninitialized LDS there can hold
    // NaN bit-patterns and PV's 0*NaN would poison the accumulator (R7 bug).
    if (RT < KB * 32) {
        for (int idx = t; idx < 64 * 16; idx += 256) {
            const int dd = idx >> 4, cc = RT + (idx & 15);
            if (cc < KB * 32) Vs[dd][cc] = 0;
        }
    }
    __syncthreads();

    // ---- QKV: one pass over row-tiles; K,Q,V together; A-frags from LDS ----
    #pragma unroll
    for (int rt = 0; rt < 5; ++rt) {
        if (rt < NT) {
            const bf16x8 a0 = *(const bf16x8*)&h1s[rt * 16 + lr][lg * 8];
            const bf16x8 a1 = *(const bf16x8*)&h1s[rt * 16 + lr][32 + lg * 8];
            f32x4 dK = {0,0,0,0}, dQ = {0,0,0,0}, dV = {0,0,0,0};
            dK = __builtin_amdgcn_mfma_f32_16x16x32_bf16(a0, wK0, dK, 0, 0, 0);
            dK = __builtin_amdgcn_mfma_f32_16x16x32_bf16(a1, wK1, dK, 0, 0, 0);
            dQ = __builtin_amdgcn_mfma_f32_16x16x32_bf16(a0, wQ0, dQ, 0, 0, 0);
            dQ = __builtin_amdgcn_mfma_f32_16x16x32_bf16(a1, wQ1, dQ, 0, 0, 0);
            dV = __builtin_amdgcn_mfma_f32_16x16x32_bf16(a0, wV0, dV, 0, 0, 0);
            dV = __builtin_amdgcn_mfma_f32_16x16x32_bf16(a1, wV1, dV, 0, 0, 0);
            const int n4 = rt * 16 + lg * 4;
            #pragma unroll
            for (int r = 0; r < 4; ++r) {
                Ks[n4 + r][ct * 16 + lr] = f2bf(dK[r] + bK);
                Qs[n4 + r][ct * 16 + lr] = f2bf(dQ[r] + bQ);
            }
            union { unsigned short us[4]; uint2 u2; } pk;
            #pragma unroll
            for (int r = 0; r < 4; ++r) pk.us[r] = f2bf(dV[r] + bV);
            *(uint2*)&Vs[ct * 16 + lr][n4] = pk.u2;   // packed 8B, key-contig
        }
    }
    __syncthreads();   // QKV done AND h1s (=Ps) dead -> attention may write Ps

    bf16x8 ones;
    #pragma unroll
    for (int j = 0; j < 8; ++j) ones[j] = (short)0x3F80;   // bf16 1.0

    // ---- dense in-segment attention; wave owns q-tile qt ----
    for (int qt = wv; qt < NT; qt += 4) {
        const bf16x8 qf0 = *(const bf16x8*)&Qs[qt * 16 + lr][lg * 8];
        const bf16x8 qf1 = *(const bf16x8*)&Qs[qt * 16 + lr][32 + lg * 8];
        for (int kt = 0; kt < 2 * KB; ++kt) {
            if (kt < NT) {
                const bf16x8 kf0 = *(const bf16x8*)&Ks[kt * 16 + lr][lg * 8];
                const bf16x8 kf1 = *(const bf16x8*)&Ks[kt * 16 + lr][32 + lg * 8];
                f32x4 dsc = {0.f, 0.f, 0.f, 0.f};
                dsc = __builtin_amdgcn_mfma_f32_16x16x32_bf16(qf0, kf0, dsc, 0, 0, 0);
                dsc = __builtin_amdgcn_mfma_f32_16x16x32_bf16(qf1, kf1, dsc, 0, 0, 0);
                const bool valid = (kt * 16 + lr) < R;   // uniform in-segment mask
                #pragma unroll
                for (int r = 0; r < 4; ++r)
                    Ps[qt * 16 + lg * 4 + r][kt * 16 + lr] =
                        valid ? f2bf(__expf(dsc[r] * SCALE)) : 0;
            } else {
                #pragma unroll
                for (int r = 0; r < 4; ++r)
                    Ps[qt * 16 + lg * 4 + r][kt * 16 + lr] = 0;
            }
        }
        asm volatile("s_waitcnt lgkmcnt(0)" ::: "memory");  // same-wave LDS RAW

        f32x4 o0 = {0,0,0,0}, o1 = {0,0,0,0}, o2 = {0,0,0,0}, o3 = {0,0,0,0};
        f32x4 sac = {0,0,0,0};
        for (int kb = 0; kb < KB; ++kb) {
            const bf16x8 pa = *(const bf16x8*)&Ps[qt * 16 + lr][kb * 32 + lg * 8];
            sac = __builtin_amdgcn_mfma_f32_16x16x32_bf16(pa, ones, sac, 0, 0, 0);
            const bf16x8 v0 = *(const bf16x8*)&Vs[lr][kb * 32 + lg * 8];
            const bf16x8 v1 = *(const bf16x8*)&Vs[16 + lr][kb * 32 + lg * 8];
            const bf16x8 v2 = *(const bf16x8*)&Vs[32 + lr][kb * 32 + lg * 8];
            const bf16x8 v3 = *(const bf16x8*)&Vs[48 + lr][kb * 32 + lg * 8];
            o0 = __builtin_amdgcn_mfma_f32_16x16x32_bf16(pa, v0, o0, 0, 0, 0);
            o1 = __builtin_amdgcn_mfma_f32_16x16x32_bf16(pa, v1, o1, 0, 0, 0);
            o2 = __builtin_amdgcn_mfma_f32_16x16x32_bf16(pa, v2, o2, 0, 0, 0);
            o3 = __builtin_amdgcn_mfma_f32_16x16x32_bf16(pa, v3, o3, 0, 0, 0);
        }

        // ---- epilogue: normalize, bounce O through this qt's (dead) Ps rows,
        // then coalesced 16B-per-lane global stores ----
        #pragma unroll
        for (int r = 0; r < 4; ++r) {
            const float inv = 1.f / sac[r];
            const int q = qt * 16 + lg * 4 + r;
            Ps[q][lr]      = f2bf(o0[r] * inv);
            Ps[q][16 + lr] = f2bf(o1[r] * inv);
            Ps[q][32 + lr] = f2bf(o2[r] * inv);
            Ps[q][48 + lr] = f2bf(o3[r] * inv);
        }
        asm volatile("s_waitcnt lgkmcnt(0)" ::: "memory");  // same-wave LDS RAW
        #pragma unroll
        for (int pass = 0; pass < 2; ++pass) {
            const int qi = pass * 8 + (lane >> 3);    // row within tile, 0..15
            const int q  = qt * 16 + qi;
            const int dd = (lane & 7) * 8;
            if (q < R)
                *(bf16x8*)(attb + (size_t)(s + q) * D + h * 64 + dd) =
                    *(const bf16x8*)&Ps[q][dd];
        }
    }
}

// ---------------------------------------------------------------------------
// Kernel C: LN2 over D=512 + out projection. Vectorized bf16x8 input loads.
// ---------------------------------------------------------------------------
__global__ __launch_bounds__(256) void ln2_out_kernel(
    const unsigned short* __restrict__ att, const float* __restrict__ g,
    const float* __restrict__ b, const unsigned short* __restrict__ Wot,
    const float* __restrict__ bias, float* __restrict__ y)
{
    __shared__ unsigned short h2[16][520];
    const int t = threadIdx.x, lane = t & 63, wv = t >> 6;
    const int row0 = blockIdx.x * 16;
    const int lr = lane & 15, lg = lane >> 4;

    const float4 ga = *(const float4*)&g[lane * 8];
    const float4 gb = *(const float4*)&g[lane * 8 + 4];
    const float4 ba = *(const float4*)&b[lane * 8];
    const float4 bb = *(const float4*)&b[lane * 8 + 4];
    const float gv[8] = {ga.x, ga.y, ga.z, ga.w, gb.x, gb.y, gb.z, gb.w};
    const float bv[8] = {ba.x, ba.y, ba.z, ba.w, bb.x, bb.y, bb.z, bb.w};

    #pragma unroll
    for (int i = 0; i < 4; ++i) {
        const int r = wv * 4 + i;
        const bf16x8 v8 = *(const bf16x8*)(att + (size_t)(row0 + r) * D + lane * 8);
        float vals[8];
        float sm = 0.f, sq = 0.f;
        #pragma unroll
        for (int c = 0; c < 8; ++c) {
            vals[c] = bf2f((unsigned short)v8[c]);
            sm += vals[c];
            sq += vals[c] * vals[c];
        }
        #pragma unroll
        for (int off = 1; off < 64; off <<= 1) {
            sm += __shfl_xor(sm, off);
            sq += __shfl_xor(sq, off);
        }
        const float mean = sm * (1.f / 512.f);
        const float var  = sq * (1.f / 512.f) - mean * mean;
        const float rstd = rsqrtf(var + EPS);
        bf16x8 hv;
        #pragma unroll
        for (int c = 0; c < 8; ++c)
            hv[c] = (short)f2bf((vals[c] - mean) * rstd * gv[c] + bv[c]);
        *(bf16x8*)&h2[r][lane * 8] = hv;              // one 16B LDS store
    }
    __syncthreads();

    const int j0 = wv * 16;
    f32x4 acc = {0.f, 0.f, 0.f, 0.f};
    #pragma unroll
    for (int ks = 0; ks < 16; ++ks) {
        const bf16x8 a  = *(const bf16x8*)&h2[lr][ks * 32 + lg * 8];
        const bf16x8 wb = *(const bf16x8*)&Wot[(size_t)(j0 + lr) * D + ks * 32 + lg * 8];
        acc = __builtin_amdgcn_mfma_f32_16x16x32_bf16(a, wb, acc, 0, 0, 0);
    }
    const float bj = bias[j0 + lr];
    #pragma unroll
    for (int r = 0; r < 4; ++r)
        y[(size_t)(row0 + lg * 4 + r) * 64 + j0 + lr] = acc[r] + bj;
}

// ---------------------------------------------------------------------------
extern "C" void kernel_launch(void* const* d_in, const int* in_sizes, int n_in,
                              void* d_out, int out_size, void* d_ws, size_t ws_size,
                              hipStream_t stream) {
    const float* x     = (const float*)d_in[0];
    const int*   batch = (const int*)  d_in[1];
    const float* ln1_g = (const float*)d_in[2];
    const float* ln1_b = (const float*)d_in[3];
    const float* W_qkv = (const float*)d_in[4];
    const float* b_qkv = (const float*)d_in[5];
    const float* ln2_g = (const float*)d_in[6];
    const float* ln2_b = (const float*)d_in[7];
    const float* W_out = (const float*)d_in[8];
    const float* b_out = (const float*)d_in[9];
    float* y = (float*)d_out;

    unsigned short* Wt   = (unsigned short*)d_ws;         // [1536][64] bf16
    unsigned short* Wot  = Wt  + (size_t)TD * 64;         // [64][512] bf16
    unsigned short* attb = Wot + (size_t)64 * D;          // [N][512] bf16
    int* bound = (int*)(attb + (size_t)N * D);            // [257]

    hipLaunchKernelGGL(prep_kernel, dim3(32), dim3(256), 0, stream,
                       W_qkv, W_out, batch, Wt, Wot, bound);
    hipLaunchKernelGGL(seghead_kernel, dim3(256, 8), dim3(256), 0, stream,
                       x, ln1_g, ln1_b, Wt, b_qkv, bound, attb);
    hipLaunchKernelGGL(ln2_out_kernel, dim3(N / 16), dim3(256), 0, stream,
                       attb, ln2_g, ln2_b, Wot, b_out, y);
}

// Round 11
// 35.485 us; speedup vs baseline: 1.2410x; 1.2410x over previous
//
#include <hip/hip_runtime.h>
#include <math.h>

#define N 6144
#define E 64
#define H 8
#define D 512
#define TD 1536  // 3*D
#define EPS 1e-5f
#define SCALE 0.04419417382415922f  // 1/sqrt(512)
#define RMAX 80                     // max supported segment size

typedef __attribute__((ext_vector_type(8))) short bf16x8;
typedef __attribute__((ext_vector_type(4))) float f32x4;

static __device__ __forceinline__ unsigned short f2bf(float f) {
    union { float f; unsigned int u; } v; v.f = f;
    unsigned int r = v.u + 0x7FFFu + ((v.u >> 16) & 1u);  // RNE
    return (unsigned short)(r >> 16);
}
static __device__ __forceinline__ float bf2f(unsigned short u) {
    union { unsigned int u; float f; } v; v.u = ((unsigned int)u) << 16;
    return v.f;
}

// ---------------------------------------------------------------------------
// Kernel 0: prep. Blocks [0,32): bound table + Wt/Wot bf16 transposes.
// Blocks [32,1568): LN1 -> h1 bf16 [N][64], one row per wave (full
// parallelism — R10 post-mortem: recomputing LN1 per (segment,head) block
// was 10x redundant serial-chain work and regressed 35->44 us).
// ---------------------------------------------------------------------------
__global__ __launch_bounds__(256) void prep_kernel(
    const float* __restrict__ x, const float* __restrict__ ln1g,
    const float* __restrict__ ln1b, const float* __restrict__ W_qkv,
    const float* __restrict__ W_out, const int* __restrict__ batch,
    unsigned short* __restrict__ Wt, unsigned short* __restrict__ Wot,
    int* __restrict__ bound, unsigned short* __restrict__ h1g)
{
    const int t = threadIdx.x, lane = t & 63, wv = t >> 6;
    if (blockIdx.x < 32) {
        const int tid = blockIdx.x * 256 + t;
        if (tid < N) {
            const int bv = batch[tid];
            const int prev = tid ? batch[tid - 1] : -1;
            if (bv != prev)
                for (int v = prev + 1; v <= bv; ++v) bound[v] = tid;
            if (tid == N - 1)
                for (int v = bv + 1; v <= 256; ++v) bound[v] = N;
        }
        for (int i = tid; i < 64 * TD; i += 8192) {    // Wt[j][k] = W[k][j]
            const int k = i / TD, j = i - k * TD;
            Wt[j * 64 + k] = f2bf(W_qkv[i]);
        }
        for (int i = tid; i < 512 * 64; i += 8192) {   // Wot[j][k] = Wo[k][j]
            const int k = i >> 6, j = i & 63;
            Wot[j * 512 + k] = f2bf(W_out[i]);
        }
    } else {
        const int row = (blockIdx.x - 32) * 4 + wv;    // [0, 6144)
        const float v = x[(size_t)row * E + lane];
        float sm = v, sq = v * v;
        #pragma unroll
        for (int off = 1; off < 64; off <<= 1) {
            sm += __shfl_xor(sm, off);
            sq += __shfl_xor(sq, off);
        }
        const float mean = sm * (1.f / 64.f);
        const float var  = sq * (1.f / 64.f) - mean * mean;
        h1g[(size_t)row * 64 + lane] =
            f2bf((v - mean) * rsqrtf(var + EPS) * ln1g[lane] + ln1b[lane]);
    }
}

// ---------------------------------------------------------------------------
// Kernel 1: one block per (segment, head). Wave wv owns column-tile ct=wv of
// K,Q,V (W-frags hoisted; h1 A-frags loaded once per row-tile). One sync,
// dense in-segment attention, O bounced through (dead) Ps rows for coalesced
// 16B global stores. Grid (256,8): the 8 head-blocks of a segment have flat
// idx = b mod 8 — same XCD under round-robin, good h1g L2 sharing. Frag maps
// (verified R3-R9): A[row=lr][k=lg*8+j], B[col=lr][k=lg*8+j],
// D[col=lr][row=lg*4+r].
// ---------------------------------------------------------------------------
__global__ __launch_bounds__(256) void seghead_kernel(
    const unsigned short* __restrict__ h1g, const unsigned short* __restrict__ Wt,
    const float* __restrict__ b_qkv, const int* __restrict__ bound,
    unsigned short* __restrict__ attb)
{
    __shared__ unsigned short Qs[RMAX][72];     // per-head Q [q][d]
    __shared__ unsigned short Ks[RMAX][72];     // per-head K [key][d]
    __shared__ unsigned short Vs[64][104];      // per-head V^T [d][key]
    __shared__ unsigned short Ps[RMAX][104];    // P bf16 [q][key] / O bounce

    const int t = threadIdx.x, lane = t & 63, wv = t >> 6;
    const int lr = lane & 15, lg = lane >> 4;
    const int b = blockIdx.x, h = blockIdx.y;

    // bound loads first: longest scalar dependency chain (R -> NT/KB/loops)
    const int s = bound[b];
    const int e = bound[b + 1];

    // W fragments for this wave's column tile (overlap under bound latency)
    const int ct = wv;
    const int jK = h * 64 + ct * 16;
    const int jQ = 512 + jK;
    const int jV = 1024 + jK;
    const bf16x8 wK0 = *(const bf16x8*)&Wt[(size_t)(jK + lr) * 64 + lg * 8];
    const bf16x8 wK1 = *(const bf16x8*)&Wt[(size_t)(jK + lr) * 64 + 32 + lg * 8];
    const bf16x8 wQ0 = *(const bf16x8*)&Wt[(size_t)(jQ + lr) * 64 + lg * 8];
    const bf16x8 wQ1 = *(const bf16x8*)&Wt[(size_t)(jQ + lr) * 64 + 32 + lg * 8];
    const bf16x8 wV0 = *(const bf16x8*)&Wt[(size_t)(jV + lr) * 64 + lg * 8];
    const bf16x8 wV1 = *(const bf16x8*)&Wt[(size_t)(jV + lr) * 64 + 32 + lg * 8];
    const float bK = b_qkv[jK + lr];
    const float bQ = b_qkv[jQ + lr];
    const float bV = b_qkv[jV + lr];

    int R = e - s;
    if (R <= 0) return;
    if (R > RMAX) R = RMAX;             // safety clamp (P ~ 1e-19)
    const int NT = (R + 15) >> 4;       // 16-row tiles (1..5)
    const int RT = NT * 16;
    const int KB = (RT + 31) >> 5;      // 32-key blocks

    // zero V^T tail key-cols [RT, KB*32): uninitialized LDS there can hold
    // NaN bit-patterns and PV's 0*NaN would poison the accumulator (R7 bug).
    if (RT < KB * 32) {
        for (int idx = t; idx < 64 * 16; idx += 256) {
            const int dd = idx >> 4, cc = RT + (idx & 15);
            if (cc < KB * 32) Vs[dd][cc] = 0;
        }
    }

    // ---- QKV: one pass over row-tiles; K,Q,V together ----
    #pragma unroll
    for (int rt = 0; rt < 5; ++rt) {
        if (rt < NT) {
            int row = s + rt * 16 + lr;
            row = row < N ? row : N - 1;              // clamp (finite data)
            const bf16x8 a0 = *(const bf16x8*)&h1g[(size_t)row * 64 + lg * 8];
            const bf16x8 a1 = *(const bf16x8*)&h1g[(size_t)row * 64 + 32 + lg * 8];
            f32x4 dK = {0,0,0,0}, dQ = {0,0,0,0}, dV = {0,0,0,0};
            dK = __builtin_amdgcn_mfma_f32_16x16x32_bf16(a0, wK0, dK, 0, 0, 0);
            dK = __builtin_amdgcn_mfma_f32_16x16x32_bf16(a1, wK1, dK, 0, 0, 0);
            dQ = __builtin_amdgcn_mfma_f32_16x16x32_bf16(a0, wQ0, dQ, 0, 0, 0);
            dQ = __builtin_amdgcn_mfma_f32_16x16x32_bf16(a1, wQ1, dQ, 0, 0, 0);
            dV = __builtin_amdgcn_mfma_f32_16x16x32_bf16(a0, wV0, dV, 0, 0, 0);
            dV = __builtin_amdgcn_mfma_f32_16x16x32_bf16(a1, wV1, dV, 0, 0, 0);
            const int n4 = rt * 16 + lg * 4;
            #pragma unroll
            for (int r = 0; r < 4; ++r) {
                Ks[n4 + r][ct * 16 + lr] = f2bf(dK[r] + bK);
                Qs[n4 + r][ct * 16 + lr] = f2bf(dQ[r] + bQ);
            }
            union { unsigned short us[4]; uint2 u2; } pk;
            #pragma unroll
            for (int r = 0; r < 4; ++r) pk.us[r] = f2bf(dV[r] + bV);
            *(uint2*)&Vs[ct * 16 + lr][n4] = pk.u2;   // packed 8B, key-contig
        }
    }
    __syncthreads();

    bf16x8 ones;
    #pragma unroll
    for (int j = 0; j < 8; ++j) ones[j] = (short)0x3F80;   // bf16 1.0

    // ---- dense in-segment attention; wave owns q-tile qt ----
    for (int qt = wv; qt < NT; qt += 4) {
        const bf16x8 qf0 = *(const bf16x8*)&Qs[qt * 16 + lr][lg * 8];
        const bf16x8 qf1 = *(const bf16x8*)&Qs[qt * 16 + lr][32 + lg * 8];
        for (int kt = 0; kt < 2 * KB; ++kt) {
            if (kt < NT) {
                const bf16x8 kf0 = *(const bf16x8*)&Ks[kt * 16 + lr][lg * 8];
                const bf16x8 kf1 = *(const bf16x8*)&Ks[kt * 16 + lr][32 + lg * 8];
                f32x4 dsc = {0.f, 0.f, 0.f, 0.f};
                dsc = __builtin_amdgcn_mfma_f32_16x16x32_bf16(qf0, kf0, dsc, 0, 0, 0);
                dsc = __builtin_amdgcn_mfma_f32_16x16x32_bf16(qf1, kf1, dsc, 0, 0, 0);
                const bool valid = (kt * 16 + lr) < R;   // uniform in-segment mask
                #pragma unroll
                for (int r = 0; r < 4; ++r)
                    Ps[qt * 16 + lg * 4 + r][kt * 16 + lr] =
                        valid ? f2bf(__expf(dsc[r] * SCALE)) : 0;
            } else {
                #pragma unroll
                for (int r = 0; r < 4; ++r)
                    Ps[qt * 16 + lg * 4 + r][kt * 16 + lr] = 0;
            }
        }
        asm volatile("s_waitcnt lgkmcnt(0)" ::: "memory");  // same-wave LDS RAW

        f32x4 o0 = {0,0,0,0}, o1 = {0,0,0,0}, o2 = {0,0,0,0}, o3 = {0,0,0,0};
        f32x4 sac = {0,0,0,0};
        for (int kb = 0; kb < KB; ++kb) {
            const bf16x8 pa = *(const bf16x8*)&Ps[qt * 16 + lr][kb * 32 + lg * 8];
            sac = __builtin_amdgcn_mfma_f32_16x16x32_bf16(pa, ones, sac, 0, 0, 0);
            const bf16x8 v0 = *(const bf16x8*)&Vs[lr][kb * 32 + lg * 8];
            const bf16x8 v1 = *(const bf16x8*)&Vs[16 + lr][kb * 32 + lg * 8];
            const bf16x8 v2 = *(const bf16x8*)&Vs[32 + lr][kb * 32 + lg * 8];
            const bf16x8 v3 = *(const bf16x8*)&Vs[48 + lr][kb * 32 + lg * 8];
            o0 = __builtin_amdgcn_mfma_f32_16x16x32_bf16(pa, v0, o0, 0, 0, 0);
            o1 = __builtin_amdgcn_mfma_f32_16x16x32_bf16(pa, v1, o1, 0, 0, 0);
            o2 = __builtin_amdgcn_mfma_f32_16x16x32_bf16(pa, v2, o2, 0, 0, 0);
            o3 = __builtin_amdgcn_mfma_f32_16x16x32_bf16(pa, v3, o3, 0, 0, 0);
        }

        // ---- epilogue: normalize, bounce O through this qt's (dead) Ps rows,
        // then coalesced 16B-per-lane global stores ----
        #pragma unroll
        for (int r = 0; r < 4; ++r) {
            const float inv = 1.f / sac[r];
            const int q = qt * 16 + lg * 4 + r;
            Ps[q][lr]      = f2bf(o0[r] * inv);
            Ps[q][16 + lr] = f2bf(o1[r] * inv);
            Ps[q][32 + lr] = f2bf(o2[r] * inv);
            Ps[q][48 + lr] = f2bf(o3[r] * inv);
        }
        asm volatile("s_waitcnt lgkmcnt(0)" ::: "memory");  // same-wave LDS RAW
        #pragma unroll
        for (int pass = 0; pass < 2; ++pass) {
            const int qi = pass * 8 + (lane >> 3);    // row within tile, 0..15
            const int q  = qt * 16 + qi;
            const int dd = (lane & 7) * 8;
            if (q < R)
                *(bf16x8*)(attb + (size_t)(s + q) * D + h * 64 + dd) =
                    *(const bf16x8*)&Ps[q][dd];
        }
    }
}

// ---------------------------------------------------------------------------
// Kernel C: LN2 over D=512 + out projection. Vectorized bf16x8 input loads.
// ---------------------------------------------------------------------------
__global__ __launch_bounds__(256) void ln2_out_kernel(
    const unsigned short* __restrict__ att, const float* __restrict__ g,
    const float* __restrict__ b, const unsigned short* __restrict__ Wot,
    const float* __restrict__ bias, float* __restrict__ y)
{
    __shared__ unsigned short h2[16][520];
    const int t = threadIdx.x, lane = t & 63, wv = t >> 6;
    const int row0 = blockIdx.x * 16;
    const int lr = lane & 15, lg = lane >> 4;

    const float4 ga = *(const float4*)&g[lane * 8];
    const float4 gb = *(const float4*)&g[lane * 8 + 4];
    const float4 ba = *(const float4*)&b[lane * 8];
    const float4 bb = *(const float4*)&b[lane * 8 + 4];
    const float gv[8] = {ga.x, ga.y, ga.z, ga.w, gb.x, gb.y, gb.z, gb.w};
    const float bv[8] = {ba.x, ba.y, ba.z, ba.w, bb.x, bb.y, bb.z, bb.w};

    #pragma unroll
    for (int i = 0; i < 4; ++i) {
        const int r = wv * 4 + i;
        const bf16x8 v8 = *(const bf16x8*)(att + (size_t)(row0 + r) * D + lane * 8);
        float vals[8];
        float sm = 0.f, sq = 0.f;
        #pragma unroll
        for (int c = 0; c < 8; ++c) {
            vals[c] = bf2f((unsigned short)v8[c]);
            sm += vals[c];
            sq += vals[c] * vals[c];
        }
        #pragma unroll
        for (int off = 1; off < 64; off <<= 1) {
            sm += __shfl_xor(sm, off);
            sq += __shfl_xor(sq, off);
        }
        const float mean = sm * (1.f / 512.f);
        const float var  = sq * (1.f / 512.f) - mean * mean;
        const float rstd = rsqrtf(var + EPS);
        bf16x8 hv;
        #pragma unroll
        for (int c = 0; c < 8; ++c)
            hv[c] = (short)f2bf((vals[c] - mean) * rstd * gv[c] + bv[c]);
        *(bf16x8*)&h2[r][lane * 8] = hv;              // one 16B LDS store
    }
    __syncthreads();

    const int j0 = wv * 16;
    f32x4 acc = {0.f, 0.f, 0.f, 0.f};
    #pragma unroll
    for (int ks = 0; ks < 16; ++ks) {
        const bf16x8 a  = *(const bf16x8*)&h2[lr][ks * 32 + lg * 8];
        const bf16x8 wb = *(const bf16x8*)&Wot[(size_t)(j0 + lr) * D + ks * 32 + lg * 8];
        acc = __builtin_amdgcn_mfma_f32_16x16x32_bf16(a, wb, acc, 0, 0, 0);
    }
    const float bj = bias[j0 + lr];
    #pragma unroll
    for (int r = 0; r < 4; ++r)
        y[(size_t)(row0 + lg * 4 + r) * 64 + j0 + lr] = acc[r] + bj;
}

// ---------------------------------------------------------------------------
extern "C" void kernel_launch(void* const* d_in, const int* in_sizes, int n_in,
                              void* d_out, int out_size, void* d_ws, size_t ws_size,
                              hipStream_t stream) {
    const float* x     = (const float*)d_in[0];
    const int*   batch = (const int*)  d_in[1];
    const float* ln1_g = (const float*)d_in[2];
    const float* ln1_b = (const float*)d_in[3];
    const float* W_qkv = (const float*)d_in[4];
    const float* b_qkv = (const float*)d_in[5];
    const float* ln2_g = (const float*)d_in[6];
    const float* ln2_b = (const float*)d_in[7];
    const float* W_out = (const float*)d_in[8];
    const float* b_out = (const float*)d_in[9];
    float* y = (float*)d_out;

    unsigned short* Wt   = (unsigned short*)d_ws;         // [1536][64] bf16
    unsigned short* Wot  = Wt  + (size_t)TD * 64;         // [64][512] bf16
    unsigned short* h1g  = Wot + (size_t)64 * D;          // [N][64] bf16
    unsigned short* attb = h1g + (size_t)N * 64;          // [N][512] bf16
    int* bound = (int*)(attb + (size_t)N * D);            // [257]

    hipLaunchKernelGGL(prep_kernel, dim3(1568), dim3(256), 0, stream,
                       x, ln1_g, ln1_b, W_qkv, W_out, batch, Wt, Wot, bound, h1g);
    hipLaunchKernelGGL(seghead_kernel, dim3(256, 8), dim3(256), 0, stream,
                       h1g, Wt, b_qkv, bound, attb);
    hipLaunchKernelGGL(ln2_out_kernel, dim3(N / 16), dim3(256), 0, stream,
                       attb, ln2_g, ln2_b, Wot, b_out, y);
}